// Round 1
// baseline (310.966 us; speedup 1.0000x reference)
//
#include <hip/hip_runtime.h>

// Problem constants (fixed by setup_inputs)
#define T_STEPS 1000
#define BSZ     512
#define CDIM    64

__device__ __forceinline__ float izh_v(float v, float u, float i) {
    // v + TAU_DT*(SQ*v*v + MN*v + BIAS - u + i), TAU_DT=0.25
    return v + 0.25f * (0.04f * v * v + 5.0f * v + 140.0f - u + i);
}
__device__ __forceinline__ float izh_u(float v, float u) {
    // u + TAU_DT*A*(B_P*v - u)
    return u + 0.25f * (0.02f * (0.2f * v - u));
}

// Kernel A: s[row] = sum over C of xs[row, :]   (row = t*B + b)
// 16 lanes per row, each loads a float4 -> wave reads 4 contiguous rows (1 KiB).
__global__ __launch_bounds__(256) void rowsum_kernel(const float* __restrict__ xs,
                                                     float* __restrict__ s) {
    int g   = blockIdx.x * 256 + threadIdx.x;
    int row = g >> 4;
    int sub = g & 15;
    float4 v = reinterpret_cast<const float4*>(xs)[row * 16 + sub];
    float t = (v.x + v.y) + (v.z + v.w);
    t += __shfl_xor(t, 1);
    t += __shfl_xor(t, 2);
    t += __shfl_xor(t, 4);
    t += __shfl_xor(t, 8);
    if (sub == 0) s[row] = t;
}

// Kernel B: per-batch-element Izhikevich recurrence over T steps.
// io holds s[t*B+b] on entry; each thread overwrites its element with z2 after reading.
__global__ __launch_bounds__(64) void recurrence_kernel(
    const float* __restrict__ b1, const float* __restrict__ W2,
    const float* __restrict__ b2, const float* __restrict__ Wg2,
    const float* __restrict__ bg2, const float* __restrict__ W3,
    const float* __restrict__ b3, float* __restrict__ io) {
    const int b = blockIdx.x * 64 + threadIdx.x;

    // Fold tiny linear layers into scalars (redundant per-thread; all cached).
    float S20 = 0.f, S21 = 0.f, d0 = 0.f, d1 = 0.f;
#pragma unroll
    for (int j = 0; j < CDIM; ++j) {
        float w0 = W2[j], w1 = W2[CDIM + j], bj = b1[j];
        S20 += w0; S21 += w1;
        d0 += w0 * bj; d1 += w1 * bj;
    }
    const float c20 = d0 + b2[0];
    const float c21 = d1 + b2[1];
    const float w30 = W3[0], w31 = W3[1];
    const float G0 = Wg2[0] * w30 + Wg2[2] * w31;  // coeff of z1[:,0]
    const float G1 = Wg2[1] * w30 + Wg2[3] * w31;  // coeff of z1[:,1]
    const float c3 = bg2[0] * w30 + bg2[1] * w31 + b3[0];

    float v0 = -70.f, u0 = -14.f;
    float v1 = -70.f, u1 = -14.f;
    float v2 = -70.f, u2 = -14.f;

    for (int t = 0; t < T_STEPS; ++t) {
        const float s = io[t * BSZ + b];
        const float i0 = s * S20 + c20;
        const float i1 = s * S21 + c21;

        // layer-1 neuron 0
        float vp0 = izh_v(v0, u0, i0);
        float up0 = izh_u(v0, u0);
        bool  z0  = (vp0 - 30.0f) > 0.0f;
        float nu0 = u0 + 6.0f;              // reset uses OLD u (+ D_P)
        v0 = z0 ? -65.0f : vp0;
        u0 = z0 ? nu0 : up0;

        // layer-1 neuron 1
        float vp1 = izh_v(v1, u1, i1);
        float up1 = izh_u(v1, u1);
        bool  z1  = (vp1 - 30.0f) > 0.0f;
        float nu1 = u1 + 6.0f;
        v1 = z1 ? -65.0f : vp1;
        u1 = z1 ? nu1 : up1;

        // folded gaining_layer_2 + W3
        const float g2 = (z0 ? G0 : 0.0f) + (z1 ? G1 : 0.0f) + c3;

        // layer-2 neuron
        float vp2 = izh_v(v2, u2, g2);
        float up2 = izh_u(v2, u2);
        bool  z2  = (vp2 - 30.0f) > 0.0f;
        float nu2 = u2 + 6.0f;
        v2 = z2 ? -65.0f : vp2;
        u2 = z2 ? nu2 : up2;

        io[t * BSZ + b] = z2 ? 1.0f : 0.0f;
    }
}

extern "C" void kernel_launch(void* const* d_in, const int* in_sizes, int n_in,
                              void* d_out, int out_size, void* d_ws, size_t ws_size,
                              hipStream_t stream) {
    const float* xs  = (const float*)d_in[0];
    const float* b1  = (const float*)d_in[2];
    const float* W2  = (const float*)d_in[3];
    const float* b2  = (const float*)d_in[4];
    const float* Wg2 = (const float*)d_in[5];
    const float* bg2 = (const float*)d_in[6];
    const float* W3  = (const float*)d_in[7];
    const float* b3  = (const float*)d_in[8];
    float* out = (float*)d_out;

    const int rows = T_STEPS * BSZ;                 // 512000
    const int blocksA = rows * 16 / 256;            // 16 lanes/row, 256 thr/block
    rowsum_kernel<<<blocksA, 256, 0, stream>>>(xs, out);
    recurrence_kernel<<<BSZ / 64, 64, 0, stream>>>(b1, W2, b2, Wg2, bg2, W3, b3, out);
}

// Round 2
// 142.077 us; speedup vs baseline: 2.1887x; 2.1887x over previous
//
#include <hip/hip_runtime.h>

// Problem constants (fixed by setup_inputs)
#define T_STEPS 1000
#define BSZ     512
#define CDIM    64
#define PF      20     // prefetch depth; 1000 % 20 == 0

__device__ __forceinline__ float izh_v(float v, float u, float i) {
    // v + TAU_DT*(SQ*v*v + MN*v + BIAS - u + i), TAU_DT=0.25
    return v + 0.25f * (0.04f * v * v + 5.0f * v + 140.0f - u + i);
}
__device__ __forceinline__ float izh_u(float v, float u) {
    // u + TAU_DT*A*(B_P*v - u)
    return u + 0.25f * (0.02f * (0.2f * v - u));
}

// Kernel A: s[row] = sum over C of xs[row, :]   (row = t*B + b)
// 16 lanes per row, each loads a float4 -> wave reads 4 contiguous rows (1 KiB).
__global__ __launch_bounds__(256) void rowsum_kernel(const float* __restrict__ xs,
                                                     float* __restrict__ s) {
    int g   = blockIdx.x * 256 + threadIdx.x;
    int row = g >> 4;
    int sub = g & 15;
    float4 v = reinterpret_cast<const float4*>(xs)[row * 16 + sub];
    float t = (v.x + v.y) + (v.z + v.w);
    t += __shfl_xor(t, 1);
    t += __shfl_xor(t, 2);
    t += __shfl_xor(t, 4);
    t += __shfl_xor(t, 8);
    if (sub == 0) s[row] = t;
}

// Kernel B: per-batch-element Izhikevich recurrence over T steps.
// io holds s[t*B+b] on entry; each thread overwrites its element with z2.
// Software-pipelined: prefetch PF future timesteps into registers while
// computing the current PF (loads are independent of the recurrence).
__global__ __launch_bounds__(64) void recurrence_kernel(
    const float* __restrict__ b1, const float* __restrict__ W2,
    const float* __restrict__ b2, const float* __restrict__ Wg2,
    const float* __restrict__ bg2, const float* __restrict__ W3,
    const float* __restrict__ b3, float* __restrict__ io) {
    const int b = blockIdx.x * 64 + threadIdx.x;

    // Fold tiny linear layers into scalars (redundant per-thread; all cached).
    float S20 = 0.f, S21 = 0.f, d0 = 0.f, d1 = 0.f;
#pragma unroll
    for (int j = 0; j < CDIM; ++j) {
        float w0 = W2[j], w1 = W2[CDIM + j], bj = b1[j];
        S20 += w0; S21 += w1;
        d0 += w0 * bj; d1 += w1 * bj;
    }
    const float c20 = d0 + b2[0];
    const float c21 = d1 + b2[1];
    const float w30 = W3[0], w31 = W3[1];
    const float G0 = Wg2[0] * w30 + Wg2[2] * w31;  // coeff of z1[:,0]
    const float G1 = Wg2[1] * w30 + Wg2[3] * w31;  // coeff of z1[:,1]
    const float c3 = bg2[0] * w30 + bg2[1] * w31 + b3[0];

    float v0 = -70.f, u0 = -14.f;
    float v1 = -70.f, u1 = -14.f;
    float v2 = -70.f, u2 = -14.f;

    float cur[PF], nxt[PF];
#pragma unroll
    for (int k = 0; k < PF; ++k) cur[k] = io[k * BSZ + b];

    for (int tb = 0; tb < T_STEPS / PF; ++tb) {
        const int tbase = tb * PF;

        // Prefetch next block FIRST so the loads issue before this block's
        // stores/compute (hides ~600-cycle L3/HBM latency under compute).
        if (tb + 1 < T_STEPS / PF) {
#pragma unroll
            for (int k = 0; k < PF; ++k)
                nxt[k] = io[(tbase + PF + k) * BSZ + b];
        }

#pragma unroll
        for (int k = 0; k < PF; ++k) {
            const float s = cur[k];
            const float i0 = s * S20 + c20;
            const float i1 = s * S21 + c21;

            // layer-1 neuron 0
            float vp0 = izh_v(v0, u0, i0);
            float up0 = izh_u(v0, u0);
            bool  z0  = (vp0 - 30.0f) > 0.0f;
            float nu0 = u0 + 6.0f;              // reset uses OLD u (+ D_P)
            v0 = z0 ? -65.0f : vp0;
            u0 = z0 ? nu0 : up0;

            // layer-1 neuron 1
            float vp1 = izh_v(v1, u1, i1);
            float up1 = izh_u(v1, u1);
            bool  z1  = (vp1 - 30.0f) > 0.0f;
            float nu1 = u1 + 6.0f;
            v1 = z1 ? -65.0f : vp1;
            u1 = z1 ? nu1 : up1;

            // folded gaining_layer_2 + W3
            const float g2 = (z0 ? G0 : 0.0f) + (z1 ? G1 : 0.0f) + c3;

            // layer-2 neuron
            float vp2 = izh_v(v2, u2, g2);
            float up2 = izh_u(v2, u2);
            bool  z2  = (vp2 - 30.0f) > 0.0f;
            float nu2 = u2 + 6.0f;
            v2 = z2 ? -65.0f : vp2;
            u2 = z2 ? nu2 : up2;

            io[(tbase + k) * BSZ + b] = z2 ? 1.0f : 0.0f;
        }

#pragma unroll
        for (int k = 0; k < PF; ++k) cur[k] = nxt[k];
    }
}

extern "C" void kernel_launch(void* const* d_in, const int* in_sizes, int n_in,
                              void* d_out, int out_size, void* d_ws, size_t ws_size,
                              hipStream_t stream) {
    const float* xs  = (const float*)d_in[0];
    const float* b1  = (const float*)d_in[2];
    const float* W2  = (const float*)d_in[3];
    const float* b2  = (const float*)d_in[4];
    const float* Wg2 = (const float*)d_in[5];
    const float* bg2 = (const float*)d_in[6];
    const float* W3  = (const float*)d_in[7];
    const float* b3  = (const float*)d_in[8];
    float* out = (float*)d_out;

    const int rows = T_STEPS * BSZ;                 // 512000
    const int blocksA = rows * 16 / 256;            // 16 lanes/row, 256 thr/block
    rowsum_kernel<<<blocksA, 256, 0, stream>>>(xs, out);
    recurrence_kernel<<<BSZ / 64, 64, 0, stream>>>(b1, W2, b2, Wg2, bg2, W3, b3, out);
}

// Round 3
// 137.875 us; speedup vs baseline: 2.2554x; 1.0305x over previous
//
#include <hip/hip_runtime.h>

// Problem constants (fixed by setup_inputs)
#define T_STEPS 1000
#define BSZ     512
#define CDIM    64
#define PF      25     // prefetch depth; 1000 % 25 == 0

__device__ __forceinline__ float izh_v(float v, float u, float i) {
    // v + TAU_DT*(SQ*v*v + MN*v + BIAS - u + i), TAU_DT=0.25
    return v + 0.25f * (0.04f * v * v + 5.0f * v + 140.0f - u + i);
}
__device__ __forceinline__ float izh_u(float v, float u) {
    // u + TAU_DT*A*(B_P*v - u)
    return u + 0.25f * (0.02f * (0.2f * v - u));
}

// Kernel A: s[row] = sum over C of xs[row, :]   (row = t*B + b)
// 16 lanes per row, each loads a float4 -> wave reads 4 contiguous rows (1 KiB).
__global__ __launch_bounds__(256) void rowsum_kernel(const float* __restrict__ xs,
                                                     float* __restrict__ s) {
    int g   = blockIdx.x * 256 + threadIdx.x;
    int row = g >> 4;
    int sub = g & 15;
    float4 v = reinterpret_cast<const float4*>(xs)[row * 16 + sub];
    float t = (v.x + v.y) + (v.z + v.w);
    t += __shfl_xor(t, 1);
    t += __shfl_xor(t, 2);
    t += __shfl_xor(t, 4);
    t += __shfl_xor(t, 8);
    if (sub == 0) s[row] = t;
}

// Kernel B: per-batch-element Izhikevich recurrence over T steps.
// io holds s[t*B+b] on entry; each thread overwrites its element with z2.
// Software-pipelined: prefetch PF future timesteps into REGISTERS while
// computing the current PF. __launch_bounds__(64,1) lifts the VGPR cap so
// cur[]/nxt[] stay in registers (round-1 spilled at VGPR_Count=48).
__global__ __launch_bounds__(64, 1) void recurrence_kernel(
    const float* __restrict__ b1, const float* __restrict__ W2,
    const float* __restrict__ b2, const float* __restrict__ Wg2,
    const float* __restrict__ bg2, const float* __restrict__ W3,
    const float* __restrict__ b3, float* __restrict__ io) {
    const int b = blockIdx.x * 64 + threadIdx.x;

    // Fold tiny linear layers into scalars (redundant per-thread; all cached).
    float S20 = 0.f, S21 = 0.f, d0 = 0.f, d1 = 0.f;
#pragma unroll
    for (int j = 0; j < CDIM; ++j) {
        float w0 = W2[j], w1 = W2[CDIM + j], bj = b1[j];
        S20 += w0; S21 += w1;
        d0 += w0 * bj; d1 += w1 * bj;
    }
    const float c20 = d0 + b2[0];
    const float c21 = d1 + b2[1];
    const float w30 = W3[0], w31 = W3[1];
    const float G0 = Wg2[0] * w30 + Wg2[2] * w31;  // coeff of z1[:,0]
    const float G1 = Wg2[1] * w30 + Wg2[3] * w31;  // coeff of z1[:,1]
    const float c3 = bg2[0] * w30 + bg2[1] * w31 + b3[0];

    float v0 = -70.f, u0 = -14.f;
    float v1 = -70.f, u1 = -14.f;
    float v2 = -70.f, u2 = -14.f;

    float cur[PF], nxt[PF];
#pragma unroll
    for (int k = 0; k < PF; ++k) cur[k] = io[k * BSZ + b];

    for (int tb = 0; tb < T_STEPS / PF; ++tb) {
        const int tbase = tb * PF;

        // Prefetch next block FIRST so the loads issue before this block's
        // stores/compute (hides ~600-cycle L3/HBM latency under compute).
        if (tb + 1 < T_STEPS / PF) {
#pragma unroll
            for (int k = 0; k < PF; ++k)
                nxt[k] = io[(tbase + PF + k) * BSZ + b];
        }

#pragma unroll
        for (int k = 0; k < PF; ++k) {
            const float s = cur[k];
            const float i0 = s * S20 + c20;
            const float i1 = s * S21 + c21;

            // layer-1 neuron 0
            float vp0 = izh_v(v0, u0, i0);
            float up0 = izh_u(v0, u0);
            bool  z0  = (vp0 - 30.0f) > 0.0f;
            float nu0 = u0 + 6.0f;              // reset uses OLD u (+ D_P)
            v0 = z0 ? -65.0f : vp0;
            u0 = z0 ? nu0 : up0;

            // layer-1 neuron 1
            float vp1 = izh_v(v1, u1, i1);
            float up1 = izh_u(v1, u1);
            bool  z1  = (vp1 - 30.0f) > 0.0f;
            float nu1 = u1 + 6.0f;
            v1 = z1 ? -65.0f : vp1;
            u1 = z1 ? nu1 : up1;

            // folded gaining_layer_2 + W3
            const float g2 = (z0 ? G0 : 0.0f) + (z1 ? G1 : 0.0f) + c3;

            // layer-2 neuron
            float vp2 = izh_v(v2, u2, g2);
            float up2 = izh_u(v2, u2);
            bool  z2  = (vp2 - 30.0f) > 0.0f;
            float nu2 = u2 + 6.0f;
            v2 = z2 ? -65.0f : vp2;
            u2 = z2 ? nu2 : up2;

            io[(tbase + k) * BSZ + b] = z2 ? 1.0f : 0.0f;
        }

#pragma unroll
        for (int k = 0; k < PF; ++k) cur[k] = nxt[k];
    }
}

extern "C" void kernel_launch(void* const* d_in, const int* in_sizes, int n_in,
                              void* d_out, int out_size, void* d_ws, size_t ws_size,
                              hipStream_t stream) {
    const float* xs  = (const float*)d_in[0];
    const float* b1  = (const float*)d_in[2];
    const float* W2  = (const float*)d_in[3];
    const float* b2  = (const float*)d_in[4];
    const float* Wg2 = (const float*)d_in[5];
    const float* bg2 = (const float*)d_in[6];
    const float* W3  = (const float*)d_in[7];
    const float* b3  = (const float*)d_in[8];
    float* out = (float*)d_out;

    const int rows = T_STEPS * BSZ;                 // 512000
    const int blocksA = rows * 16 / 256;            // 16 lanes/row, 256 thr/block
    rowsum_kernel<<<blocksA, 256, 0, stream>>>(xs, out);
    recurrence_kernel<<<BSZ / 64, 64, 0, stream>>>(b1, W2, b2, Wg2, bg2, W3, b3, out);
}